// Round 3
// baseline (825.396 us; speedup 1.0000x reference)
//
#include <hip/hip_runtime.h>

// Polarisation solver, CSR-gather formulation v3.
// Build: hist -> scan -> scatter PERMUTATION INDEX only (4B/edge random write)
// -> row-ordered materialize (random READS from L3-resident inputs, sequential
// payload writes, E0/mu0 folded in). Then 7 atomic-free Jacobi gather passes.

static constexpr float INV_B  = 1.0f / 0.52917721067f;            // 1/BOHR
static constexpr float INV_B3 = INV_B * INV_B * INV_B;            // 1/BOHR^3
static constexpr float DM = 0.39f;                                 // DAMP_MUTUAL
static constexpr float DF = 0.7f;                                  // DAMP_FIELD
static constexpr int   NITER = 7;
#define SCAN_B 256

// ---------------- CSR build ----------------

__global__ void hist_kernel(const int* __restrict__ esrc, int* __restrict__ cnt, int E)
{
    int e = blockIdx.x * blockDim.x + threadIdx.x;
    if (e < E) atomicAdd(&cnt[esrc[e]], 1);
}

__global__ void scan1_kernel(const int* __restrict__ cnt, int* __restrict__ excl,
                             int* __restrict__ blocksum, int n, int nvalid)
{
    __shared__ int sh[SCAN_B];
    int tid = threadIdx.x;
    int i = blockIdx.x * SCAN_B + tid;
    int v = (i < nvalid) ? cnt[i] : 0;
    sh[tid] = v;
    __syncthreads();
    for (int off = 1; off < SCAN_B; off <<= 1) {
        int t = (tid >= off) ? sh[tid - off] : 0;
        __syncthreads();
        sh[tid] += t;
        __syncthreads();
    }
    if (i < n) excl[i] = sh[tid] - v;
    if (tid == SCAN_B - 1) blocksum[blockIdx.x] = sh[tid];
}

__global__ void scan2_kernel(int* __restrict__ blocksum, int nb)
{
    __shared__ int sh[512];
    int tid = threadIdx.x;
    int v = (tid < nb) ? blocksum[tid] : 0;
    sh[tid] = v;
    __syncthreads();
    for (int off = 1; off < 512; off <<= 1) {
        int t = (tid >= off) ? sh[tid - off] : 0;
        __syncthreads();
        sh[tid] += t;
        __syncthreads();
    }
    if (tid < nb) blocksum[tid] = sh[tid] - v;
}

__global__ void scan3_kernel(int* __restrict__ rowptr, const int* __restrict__ blocksum,
                             int* __restrict__ cursor, int n)
{
    int i = blockIdx.x * SCAN_B + threadIdx.x;
    if (i < n) {
        int v = rowptr[i] + blocksum[blockIdx.x];
        rowptr[i] = v;
        if (i < n - 1) cursor[i] = v;
    }
}

// Scatter only the permutation index: perm[slot] = e  (4B random write, L3-absorbed)
__global__ void permscatter_kernel(const int* __restrict__ esrc, int* __restrict__ cursor,
                                   int* __restrict__ perm, int E)
{
    int e = blockIdx.x * blockDim.x + threadIdx.x;
    if (e >= E) return;
    int slot = atomicAdd(&cursor[esrc[e]], 1);
    perm[slot] = e;
}

// Row-ordered materialize: random-gather raw edge data via perm (L3-resident),
// recompute physics, write payload sequentially, fold E0 + mu0.
// matvec term: t = c1*mu_d - (w.mu_d)*w  with  w = sqrt(3*l5m*inv_r5)*v.
__global__ void permuteE0_kernel(const int* __restrict__ rowptr, const int* __restrict__ perm,
                                 const int* __restrict__ edst, const float* __restrict__ dist,
                                 const float* __restrict__ vec, const float* __restrict__ pol,
                                 const float* __restrict__ chg,
                                 int* __restrict__ dstA, float4* __restrict__ c1w,
                                 float4* __restrict__ E0, float4* __restrict__ mu, int N)
{
    int tid  = threadIdx.x;
    int lane = tid & 15;
    int row  = (blockIdx.x * blockDim.x + tid) >> 4;
    if (row >= N) return;
    int r0 = rowptr[row], r1 = rowptr[row + 1];
    float ps = pol[row] * INV_B3;
    float sx = 0.f, sy = 0.f, sz = 0.f;
    for (int j = r0 + lane; j < r1; j += 16) {
        int e = perm[j];
        int d = edst[e];
        float r  = dist[e] * INV_B;
        float vx = vec[3*e+0] * INV_B;
        float vy = vec[3*e+1] * INV_B;
        float vz = vec[3*e+2] * INV_B;
        float pd = pol[d] * INV_B3;
        float r2 = r * r;
        float r3 = r2 * r;
        float u  = r3 * rsqrtf(ps * pd);
        float em = __expf(-DM * u);
        float l3m = 1.0f - em;
        float l5m = 1.0f - (1.0f + DM * u) * em;
        float inv_r3 = 1.0f / r3;
        float inv_r5 = inv_r3 / r2;
        float c1 = l3m * inv_r3;
        float sw = sqrtf(3.0f * l5m * inv_r5);
        float ec = (1.0f - __expf(-DF * u)) * chg[d] * inv_r3;
        dstA[j] = d;
        c1w[j]  = make_float4(c1, sw * vx, sw * vy, sw * vz);
        sx += ec * vx;
        sy += ec * vy;
        sz += ec * vz;
    }
    for (int m = 8; m >= 1; m >>= 1) {
        sx += __shfl_xor(sx, m);
        sy += __shfl_xor(sy, m);
        sz += __shfl_xor(sz, m);
    }
    if (lane == 0) {
        E0[row] = make_float4(sx, sy, sz, 0.f);
        mu[row] = make_float4(ps * sx, ps * sy, ps * sz, 0.f);
    }
}

// ---------------- Jacobi gather pass (no atomics) ----------------

__global__ void mvgather_kernel(const int* __restrict__ rowptr, const int* __restrict__ dstA,
                                const float4* __restrict__ c1w, const float4* __restrict__ E0,
                                const float* __restrict__ pol,
                                const float4* __restrict__ mu_in, float4* __restrict__ mu_out,
                                float* __restrict__ energy, int N, int final_iter)
{
    int tid  = threadIdx.x;
    int lane = tid & 15;
    int row  = (blockIdx.x * blockDim.x + tid) >> 4;
    if (row >= N) return;
    int r0 = rowptr[row], r1 = rowptr[row + 1];
    float ax = 0.f, ay = 0.f, az = 0.f;
    for (int j = r0 + lane; j < r1; j += 16) {
        int d = dstA[j];
        float4 cw = c1w[j];
        float4 m  = mu_in[d];
        float dot = cw.y * m.x + cw.z * m.y + cw.w * m.z;
        ax += cw.x * m.x - dot * cw.y;
        ay += cw.x * m.y - dot * cw.z;
        az += cw.x * m.z - dot * cw.w;
    }
    for (int msk = 8; msk >= 1; msk >>= 1) {
        ax += __shfl_xor(ax, msk);
        ay += __shfl_xor(ay, msk);
        az += __shfl_xor(az, msk);
    }
    if (lane == 0) {
        float4 e0 = E0[row];
        float a = pol[row] * INV_B3;
        float mx = a * (e0.x - ax);
        float my = a * (e0.y - ay);
        float mz = a * (e0.z - az);
        mu_out[row] = make_float4(mx, my, mz, 0.f);
        if (final_iter)
            energy[row] = -0.5f * (mx * e0.x + my * e0.y + mz * e0.z);
    }
}

// ---------------- fallback (atomic path, tiny ws) ----------------

__global__ void fb_e0_kernel(const int* esrc, const int* edst, const float* dist,
                             const float* vec, const float* pol, const float* chg,
                             float4* E0, int E)
{
    int e = blockIdx.x * blockDim.x + threadIdx.x;
    if (e >= E) return;
    int s = esrc[e], d = edst[e];
    float r  = dist[e] * INV_B;
    float vx = vec[3*e+0]*INV_B, vy = vec[3*e+1]*INV_B, vz = vec[3*e+2]*INV_B;
    float r3 = r*r*r;
    float u  = r3 * rsqrtf(pol[s]*INV_B3 * pol[d]*INV_B3);
    float ec = (1.0f - __expf(-DF*u)) * chg[d] / r3;
    atomicAdd(&E0[s].x, ec*vx); atomicAdd(&E0[s].y, ec*vy); atomicAdd(&E0[s].z, ec*vz);
}

__global__ void fb_init_kernel(const float* pol, const float4* E0, float4* mu, float4* acc, int N)
{
    int i = blockIdx.x * blockDim.x + threadIdx.x;
    if (i >= N) return;
    float a = pol[i]*INV_B3; float4 e0 = E0[i];
    mu[i]  = make_float4(a*e0.x, a*e0.y, a*e0.z, 0.f);
    acc[i] = make_float4(0.f,0.f,0.f,0.f);
}

__global__ void fb_matvec_kernel(const int* esrc, const int* edst, const float* dist,
                                 const float* vec, const float* pol,
                                 const float4* mu, float4* acc, int E)
{
    int e = blockIdx.x * blockDim.x + threadIdx.x;
    if (e >= E) return;
    int s = esrc[e], d = edst[e];
    float r  = dist[e]*INV_B;
    float vx = vec[3*e+0]*INV_B, vy = vec[3*e+1]*INV_B, vz = vec[3*e+2]*INV_B;
    float r2 = r*r, r3 = r2*r;
    float u  = r3 * rsqrtf(pol[s]*INV_B3 * pol[d]*INV_B3);
    float em = __expf(-DM*u);
    float c1 = (1.0f - em) / r3;
    float c2 = 3.0f * (1.0f - (1.0f + DM*u)*em) / (r3*r2);
    float4 m = mu[d];
    float k = c2 * (vx*m.x + vy*m.y + vz*m.z);
    atomicAdd(&acc[s].x, c1*m.x - k*vx);
    atomicAdd(&acc[s].y, c1*m.y - k*vy);
    atomicAdd(&acc[s].z, c1*m.z - k*vz);
}

__global__ void fb_update_kernel(const float* pol, const float4* E0, float4* acc,
                                 float4* mu, float* energy, int N, int final_iter)
{
    int i = blockIdx.x * blockDim.x + threadIdx.x;
    if (i >= N) return;
    float a = pol[i]*INV_B3; float4 e0 = E0[i]; float4 ac = acc[i];
    float mx = a*(e0.x-ac.x), my = a*(e0.y-ac.y), mz = a*(e0.z-ac.z);
    mu[i]  = make_float4(mx,my,mz,0.f);
    acc[i] = make_float4(0.f,0.f,0.f,0.f);
    if (final_iter) energy[i] = -0.5f*(mx*e0.x + my*e0.y + mz*e0.z);
}

// ---------------- launch ----------------

static inline size_t align_up(size_t x, size_t a) { return (x + a - 1) & ~(a - 1); }

extern "C" void kernel_launch(void* const* d_in, const int* in_sizes, int n_in,
                              void* d_out, int out_size, void* d_ws, size_t ws_size,
                              hipStream_t stream)
{
    // inputs: species, edge_src, edge_dst, distances, vec, polarisability, charges
    const int*   esrc = (const int*)  d_in[1];
    const int*   edst = (const int*)  d_in[2];
    const float* dist = (const float*)d_in[3];
    const float* vec  = (const float*)d_in[4];
    const float* pol  = (const float*)d_in[5];
    const float* chg  = (const float*)d_in[6];
    const int E = in_sizes[1];
    const int N = in_sizes[5];
    float* out = (float*)d_out;

    const int EB = 256, NB = 256;
    const int EG = (E + EB - 1) / EB;

    // workspace layout (~82 MB for N=100k, E=3.2M)
    char* ws = (char*)d_ws;
    size_t off = 0;
    auto carve = [&](size_t bytes) { size_t o = off; off = align_up(off + bytes, 256); return o; };
    size_t o_rowptr  = carve((size_t)(N + 1) * 4);
    size_t o_cursor  = carve((size_t)N * 4);
    size_t o_E0      = carve((size_t)N * 16);
    size_t o_mua     = carve((size_t)N * 16);
    size_t o_mub     = carve((size_t)N * 16);
    size_t o_bsum    = carve(512 * 4);
    size_t o_perm    = carve((size_t)E * 4);
    size_t o_dstA    = carve((size_t)E * 4);
    size_t o_c1w     = carve((size_t)E * 16);
    size_t need = off;

    if (ws_size >= need) {
        int*    rowptr = (int*)   (ws + o_rowptr);
        int*    cursor = (int*)   (ws + o_cursor);
        float4* E0     = (float4*)(ws + o_E0);
        float4* mu_a   = (float4*)(ws + o_mua);
        float4* mu_b   = (float4*)(ws + o_mub);
        int*    bsum   = (int*)   (ws + o_bsum);
        int*    perm   = (int*)   (ws + o_perm);
        int*    dstA   = (int*)   (ws + o_dstA);
        float4* c1w    = (float4*)(ws + o_c1w);

        const int nScan = N + 1;
        const int g1 = (nScan + SCAN_B - 1) / SCAN_B;     // <= 512 for N=100k

        hipMemsetAsync(cursor, 0, (size_t)N * 4, stream);
        hist_kernel<<<EG, EB, 0, stream>>>(esrc, cursor, E);
        scan1_kernel<<<g1, SCAN_B, 0, stream>>>(cursor, rowptr, bsum, nScan, N);
        scan2_kernel<<<1, 512, 0, stream>>>(bsum, g1);
        scan3_kernel<<<g1, SCAN_B, 0, stream>>>(rowptr, bsum, cursor, nScan);
        permscatter_kernel<<<EG, EB, 0, stream>>>(esrc, cursor, perm, E);

        const int rows_per_block = NB / 16;
        const int NG16 = (N + rows_per_block - 1) / rows_per_block;
        permuteE0_kernel<<<NG16, NB, 0, stream>>>(rowptr, perm, edst, dist, vec, pol, chg,
                                                  dstA, c1w, E0, mu_a, N);

        float4* min_ = mu_a; float4* mout_ = mu_b;
        for (int it = 0; it < NITER; ++it) {
            mvgather_kernel<<<NG16, NB, 0, stream>>>(rowptr, dstA, c1w, E0, pol,
                                                     min_, mout_, out, N, it == NITER - 1);
            float4* t = min_; min_ = mout_; mout_ = t;
        }
    } else {
        // fallback: atomic scatter path (needs 48B/node)
        float4* E0  = (float4*)(ws);
        float4* mu  = (float4*)(ws + (size_t)N * 16);
        float4* acc = (float4*)(ws + (size_t)N * 32);
        const int NG = (N + NB - 1) / NB;
        hipMemsetAsync(E0, 0, (size_t)N * 16, stream);
        fb_e0_kernel<<<EG, EB, 0, stream>>>(esrc, edst, dist, vec, pol, chg, E0, E);
        fb_init_kernel<<<NG, NB, 0, stream>>>(pol, E0, mu, acc, N);
        for (int it = 0; it < NITER; ++it) {
            fb_matvec_kernel<<<EG, EB, 0, stream>>>(esrc, edst, dist, vec, pol, mu, acc, E);
            fb_update_kernel<<<NG, NB, 0, stream>>>(pol, E0, acc, mu, out, N, it == NITER - 1);
        }
    }
}

// Round 4
// 672.461 us; speedup vs baseline: 1.2274x; 1.2274x over previous
//
#include <hip/hip_runtime.h>

// Polarisation solver v4: coarse bucket decomposition, zero global random access.
// Bucket = 256 consecutive src nodes. Build: per-(block,bucket) hist -> scan ->
// single streaming pass writes 24B payload/edge into bucket-contiguous regions
// (LDS cursors). Iterations: one block per bucket streams its payload
// sequentially, gathers mu[dst] (L2-resident), accumulates in LDS (ds_add_f32),
// fused Jacobi update. No CSR, no global atomics in the iterate loop.

static constexpr float INV_B  = 1.0f / 0.52917721067f;            // 1/BOHR
static constexpr float INV_B3 = INV_B * INV_B * INV_B;            // 1/BOHR^3
static constexpr float DM = 0.39f;                                 // DAMP_MUTUAL
static constexpr float DF = 0.7f;                                  // DAMP_FIELD
static constexpr int   NITER = 7;
#define SCAN_B 256
#define CHUNK 16384
#define MAXBUCK 512

// ---------------- build: per-(block,bucket) histogram ----------------

__global__ void bhist_kernel(const int* __restrict__ esrc, int* __restrict__ h,
                             int E, int nbuck, int nblk)
{
    __shared__ int cnt[MAXBUCK];
    int tid = threadIdx.x, blk = blockIdx.x;
    for (int b = tid; b < nbuck; b += blockDim.x) cnt[b] = 0;
    __syncthreads();
    int lo = blk * CHUNK, hi = min(E, lo + CHUNK);
    for (int i = lo + tid; i < hi; i += blockDim.x)
        atomicAdd(&cnt[esrc[i] >> 8], 1);
    __syncthreads();
    for (int b = tid; b < nbuck; b += blockDim.x)
        h[b * nblk + blk] = cnt[b];                 // bucket-major for scan
}

// ---------------- generic 2-level exclusive scan ----------------

__global__ void scan1_kernel(const int* __restrict__ in, int* __restrict__ excl,
                             int* __restrict__ blocksum, int n)
{
    __shared__ int sh[SCAN_B];
    int tid = threadIdx.x;
    int i = blockIdx.x * SCAN_B + tid;
    int v = (i < n) ? in[i] : 0;
    sh[tid] = v;
    __syncthreads();
    for (int off = 1; off < SCAN_B; off <<= 1) {
        int t = (tid >= off) ? sh[tid - off] : 0;
        __syncthreads();
        sh[tid] += t;
        __syncthreads();
    }
    if (i < n) excl[i] = sh[tid] - v;
    if (tid == SCAN_B - 1) blocksum[blockIdx.x] = sh[tid];
}

__global__ void scan2_kernel(int* __restrict__ blocksum, int nb)
{
    __shared__ int sh[512];
    int tid = threadIdx.x;
    int v = (tid < nb) ? blocksum[tid] : 0;
    sh[tid] = v;
    __syncthreads();
    for (int off = 1; off < 512; off <<= 1) {
        int t = (tid >= off) ? sh[tid - off] : 0;
        __syncthreads();
        sh[tid] += t;
        __syncthreads();
    }
    if (tid < nb) blocksum[tid] = sh[tid] - v;
}

__global__ void scan3_kernel(int* __restrict__ excl, const int* __restrict__ blocksum, int n)
{
    int i = blockIdx.x * SCAN_B + threadIdx.x;
    if (i < n) excl[i] += blocksum[blockIdx.x];
}

__global__ void bktptr_kernel(const int* __restrict__ hoff, int* __restrict__ bktptr,
                              int nbuck, int nblk, int E)
{
    int b = blockIdx.x * blockDim.x + threadIdx.x;
    if (b < nbuck) bktptr[b] = hoff[b * nblk];
    if (b == nbuck) bktptr[b] = E;
}

// ---------------- build: physics + bucket-contiguous payload ----------------
// payload: dstpk = dst | (localrow<<20); cw = {c1, wx, wy, wz}; g (E0 scale).
// matvec term: t = c1*mu_d - (w.mu_d)*w, w = sqrt(3*l5m*inv_r5)*vec_ij.
// E0 term: g*w with g = l3f*q_d*inv_r3 / sw  (sw > 5e-4 always; u >= 0.5).

__global__ void build_kernel(const int* __restrict__ esrc, const int* __restrict__ edst,
                             const float* __restrict__ dist, const float* __restrict__ vec,
                             const float* __restrict__ pol, const float* __restrict__ chg,
                             const int* __restrict__ hoff,
                             int* __restrict__ dstpk, float4* __restrict__ cw,
                             float* __restrict__ gA, int E, int nbuck, int nblk)
{
    __shared__ int cur[MAXBUCK];
    int tid = threadIdx.x, blk = blockIdx.x;
    for (int b = tid; b < nbuck; b += blockDim.x) cur[b] = hoff[b * nblk + blk];
    __syncthreads();
    int lo = blk * CHUNK, hi = min(E, lo + CHUNK);
    for (int i = lo + tid; i < hi; i += blockDim.x) {
        int s = esrc[i], d = edst[i];
        float r  = dist[i] * INV_B;
        float vx = vec[3*i+0] * INV_B;
        float vy = vec[3*i+1] * INV_B;
        float vz = vec[3*i+2] * INV_B;
        float ps = pol[s] * INV_B3;
        float pd = pol[d] * INV_B3;
        float r2 = r * r;
        float r3 = r2 * r;
        float u  = r3 * rsqrtf(ps * pd);
        float em = __expf(-DM * u);
        float l3m = 1.0f - em;
        float l5m = 1.0f - (1.0f + DM * u) * em;
        float inv_r3 = 1.0f / r3;
        float inv_r5 = inv_r3 / r2;
        float c1 = l3m * inv_r3;
        float sw = sqrtf(3.0f * l5m * inv_r5);
        float ec = (1.0f - __expf(-DF * u)) * chg[d] * inv_r3;
        int slot = atomicAdd(&cur[s >> 8], 1);      // LDS cursor
        dstpk[slot] = d | ((s & 255) << 20);
        cw[slot]    = make_float4(c1, sw * vx, sw * vy, sw * vz);
        gA[slot]    = ec / sw;
    }
}

// ---------------- iterate: bucket-centric, LDS accumulation ----------------

__global__ void e0b_kernel(const int* __restrict__ bktptr, const int* __restrict__ dstpk,
                           const float4* __restrict__ cw, const float* __restrict__ gA,
                           const float* __restrict__ pol,
                           float4* __restrict__ E0, float4* __restrict__ mu, int N)
{
    __shared__ float acc[256 * 3];
    int tid = threadIdx.x, b = blockIdx.x;
    for (int k = tid; k < 768; k += 256) acc[k] = 0.f;
    __syncthreads();
    int j0 = bktptr[b], j1 = bktptr[b + 1];
    for (int j = j0 + tid; j < j1; j += 256) {
        int pk = dstpk[j];
        float4 c = cw[j];
        float g = gA[j];
        int lr = pk >> 20;
        atomicAdd(&acc[lr*3+0], g * c.y);
        atomicAdd(&acc[lr*3+1], g * c.z);
        atomicAdd(&acc[lr*3+2], g * c.w);
    }
    __syncthreads();
    int r = b * 256 + tid;
    if (r < N) {
        float ax = acc[tid*3], ay = acc[tid*3+1], az = acc[tid*3+2];
        E0[r] = make_float4(ax, ay, az, 0.f);
        float a = pol[r] * INV_B3;
        mu[r] = make_float4(a * ax, a * ay, a * az, 0.f);
    }
}

__global__ void mvb_kernel(const int* __restrict__ bktptr, const int* __restrict__ dstpk,
                           const float4* __restrict__ cw, const float4* __restrict__ E0,
                           const float* __restrict__ pol,
                           const float4* __restrict__ mu_in, float4* __restrict__ mu_out,
                           float* __restrict__ energy, int N, int final_iter)
{
    __shared__ float acc[256 * 3];
    int tid = threadIdx.x, b = blockIdx.x;
    for (int k = tid; k < 768; k += 256) acc[k] = 0.f;
    __syncthreads();
    int j0 = bktptr[b], j1 = bktptr[b + 1];
    for (int j = j0 + tid; j < j1; j += 256) {
        int pk = dstpk[j];
        float4 c = cw[j];
        float4 m = mu_in[pk & 0xFFFFF];             // random 16B, L2-resident 1.6MB
        float dot = c.y * m.x + c.z * m.y + c.w * m.z;
        int lr = pk >> 20;
        atomicAdd(&acc[lr*3+0], c.x * m.x - dot * c.y);
        atomicAdd(&acc[lr*3+1], c.x * m.y - dot * c.z);
        atomicAdd(&acc[lr*3+2], c.x * m.z - dot * c.w);
    }
    __syncthreads();
    int r = b * 256 + tid;
    if (r < N) {
        float4 e0 = E0[r];
        float a = pol[r] * INV_B3;
        float mx = a * (e0.x - acc[tid*3+0]);
        float my = a * (e0.y - acc[tid*3+1]);
        float mz = a * (e0.z - acc[tid*3+2]);
        mu_out[r] = make_float4(mx, my, mz, 0.f);
        if (final_iter)
            energy[r] = -0.5f * (mx * e0.x + my * e0.y + mz * e0.z);
    }
}

// ---------------- fallback (atomic path, tiny ws) ----------------

__global__ void fb_e0_kernel(const int* esrc, const int* edst, const float* dist,
                             const float* vec, const float* pol, const float* chg,
                             float4* E0, int E)
{
    int e = blockIdx.x * blockDim.x + threadIdx.x;
    if (e >= E) return;
    int s = esrc[e], d = edst[e];
    float r  = dist[e] * INV_B;
    float vx = vec[3*e+0]*INV_B, vy = vec[3*e+1]*INV_B, vz = vec[3*e+2]*INV_B;
    float r3 = r*r*r;
    float u  = r3 * rsqrtf(pol[s]*INV_B3 * pol[d]*INV_B3);
    float ec = (1.0f - __expf(-DF*u)) * chg[d] / r3;
    atomicAdd(&E0[s].x, ec*vx); atomicAdd(&E0[s].y, ec*vy); atomicAdd(&E0[s].z, ec*vz);
}

__global__ void fb_init_kernel(const float* pol, const float4* E0, float4* mu, float4* acc, int N)
{
    int i = blockIdx.x * blockDim.x + threadIdx.x;
    if (i >= N) return;
    float a = pol[i]*INV_B3; float4 e0 = E0[i];
    mu[i]  = make_float4(a*e0.x, a*e0.y, a*e0.z, 0.f);
    acc[i] = make_float4(0.f,0.f,0.f,0.f);
}

__global__ void fb_matvec_kernel(const int* esrc, const int* edst, const float* dist,
                                 const float* vec, const float* pol,
                                 const float4* mu, float4* acc, int E)
{
    int e = blockIdx.x * blockDim.x + threadIdx.x;
    if (e >= E) return;
    int s = esrc[e], d = edst[e];
    float r  = dist[e]*INV_B;
    float vx = vec[3*e+0]*INV_B, vy = vec[3*e+1]*INV_B, vz = vec[3*e+2]*INV_B;
    float r2 = r*r, r3 = r2*r;
    float u  = r3 * rsqrtf(pol[s]*INV_B3 * pol[d]*INV_B3);
    float em = __expf(-DM*u);
    float c1 = (1.0f - em) / r3;
    float c2 = 3.0f * (1.0f - (1.0f + DM*u)*em) / (r3*r2);
    float4 m = mu[d];
    float k = c2 * (vx*m.x + vy*m.y + vz*m.z);
    atomicAdd(&acc[s].x, c1*m.x - k*vx);
    atomicAdd(&acc[s].y, c1*m.y - k*vy);
    atomicAdd(&acc[s].z, c1*m.z - k*vz);
}

__global__ void fb_update_kernel(const float* pol, const float4* E0, float4* acc,
                                 float4* mu, float* energy, int N, int final_iter)
{
    int i = blockIdx.x * blockDim.x + threadIdx.x;
    if (i >= N) return;
    float a = pol[i]*INV_B3; float4 e0 = E0[i]; float4 ac = acc[i];
    float mx = a*(e0.x-ac.x), my = a*(e0.y-ac.y), mz = a*(e0.z-ac.z);
    mu[i]  = make_float4(mx,my,mz,0.f);
    acc[i] = make_float4(0.f,0.f,0.f,0.f);
    if (final_iter) energy[i] = -0.5f*(mx*e0.x + my*e0.y + mz*e0.z);
}

// ---------------- launch ----------------

static inline size_t align_up(size_t x, size_t a) { return (x + a - 1) & ~(a - 1); }

extern "C" void kernel_launch(void* const* d_in, const int* in_sizes, int n_in,
                              void* d_out, int out_size, void* d_ws, size_t ws_size,
                              hipStream_t stream)
{
    // inputs: species, edge_src, edge_dst, distances, vec, polarisability, charges
    const int*   esrc = (const int*)  d_in[1];
    const int*   edst = (const int*)  d_in[2];
    const float* dist = (const float*)d_in[3];
    const float* vec  = (const float*)d_in[4];
    const float* pol  = (const float*)d_in[5];
    const float* chg  = (const float*)d_in[6];
    const int E = in_sizes[1];
    const int N = in_sizes[5];
    float* out = (float*)d_out;

    const int nbuck = (N + 255) >> 8;                  // 391 for N=100k
    const int nblk  = (E + CHUNK - 1) / CHUNK;         // 196 for E=3.2M
    const int nScan = nbuck * nblk;                    // 76,636
    const int g1    = (nScan + SCAN_B - 1) / SCAN_B;   // 300

    // workspace layout (~82 MB)
    char* ws = (char*)d_ws;
    size_t off = 0;
    auto carve = [&](size_t bytes) { size_t o = off; off = align_up(off + bytes, 256); return o; };
    size_t o_h      = carve((size_t)nScan * 4);
    size_t o_hoff   = carve((size_t)nScan * 4);
    size_t o_bsum   = carve(512 * 4);
    size_t o_bkt    = carve((size_t)(nbuck + 1) * 4);
    size_t o_E0     = carve((size_t)N * 16);
    size_t o_mua    = carve((size_t)N * 16);
    size_t o_mub    = carve((size_t)N * 16);
    size_t o_dstpk  = carve((size_t)E * 4);
    size_t o_cw     = carve((size_t)E * 16);
    size_t o_g      = carve((size_t)E * 4);
    size_t need = off;

    bool ok = (ws_size >= need) && (nbuck <= MAXBUCK) && (g1 <= 512) && (nbuck >= 1);

    if (ok) {
        int*    h      = (int*)   (ws + o_h);
        int*    hoff   = (int*)   (ws + o_hoff);
        int*    bsum   = (int*)   (ws + o_bsum);
        int*    bktptr = (int*)   (ws + o_bkt);
        float4* E0     = (float4*)(ws + o_E0);
        float4* mu_a   = (float4*)(ws + o_mua);
        float4* mu_b   = (float4*)(ws + o_mub);
        int*    dstpk  = (int*)   (ws + o_dstpk);
        float4* cwA    = (float4*)(ws + o_cw);
        float*  gA     = (float*) (ws + o_g);

        bhist_kernel<<<nblk, 256, 0, stream>>>(esrc, h, E, nbuck, nblk);
        scan1_kernel<<<g1, SCAN_B, 0, stream>>>(h, hoff, bsum, nScan);
        scan2_kernel<<<1, 512, 0, stream>>>(bsum, g1);
        scan3_kernel<<<g1, SCAN_B, 0, stream>>>(hoff, bsum, nScan);
        bktptr_kernel<<<(nbuck + 256) / 256, 256, 0, stream>>>(hoff, bktptr, nbuck, nblk, E);
        build_kernel<<<nblk, 256, 0, stream>>>(esrc, edst, dist, vec, pol, chg,
                                               hoff, dstpk, cwA, gA, E, nbuck, nblk);

        e0b_kernel<<<nbuck, 256, 0, stream>>>(bktptr, dstpk, cwA, gA, pol, E0, mu_a, N);

        float4* min_ = mu_a; float4* mout_ = mu_b;
        for (int it = 0; it < NITER; ++it) {
            mvb_kernel<<<nbuck, 256, 0, stream>>>(bktptr, dstpk, cwA, E0, pol,
                                                  min_, mout_, out, N, it == NITER - 1);
            float4* t = min_; min_ = mout_; mout_ = t;
        }
    } else {
        // fallback: atomic scatter path (needs 48B/node)
        float4* E0  = (float4*)(ws);
        float4* mu  = (float4*)(ws + (size_t)N * 16);
        float4* acc = (float4*)(ws + (size_t)N * 32);
        const int EB = 256, NB = 256;
        const int EG = (E + EB - 1) / EB;
        const int NG = (N + NB - 1) / NB;
        hipMemsetAsync(E0, 0, (size_t)N * 16, stream);
        fb_e0_kernel<<<EG, EB, 0, stream>>>(esrc, edst, dist, vec, pol, chg, E0, E);
        fb_init_kernel<<<NG, NB, 0, stream>>>(pol, E0, mu, acc, N);
        for (int it = 0; it < NITER; ++it) {
            fb_matvec_kernel<<<EG, EB, 0, stream>>>(esrc, edst, dist, vec, pol, mu, acc, E);
            fb_update_kernel<<<NG, NB, 0, stream>>>(pol, E0, acc, mu, out, N, it == NITER - 1);
        }
    }
}

// Round 5
// 625.794 us; speedup vs baseline: 1.3190x; 1.0746x over previous
//
#include <hip/hip_runtime.h>
#include <hip/hip_fp16.h>

// Polarisation solver v5: bucket decomposition with single 16B AoS payload record.
// record = {dst|(localrow<<20), c1 f32, wx|wy f16x2, wz|g f16x2}.
// Build: per-(block,bucket) hist -> scan -> streaming pass writes one uint4 per
// edge into bucket-contiguous regions (LDS cursors, 1 write stream per bucket).
// Iterate: one block per bucket streams records sequentially, gathers mu[dst]
// (L2-resident 1.6MB), accumulates in LDS, fused Jacobi update. No global atomics.

static constexpr float INV_B  = 1.0f / 0.52917721067f;            // 1/BOHR
static constexpr float INV_B3 = INV_B * INV_B * INV_B;            // 1/BOHR^3
static constexpr float DM = 0.39f;                                 // DAMP_MUTUAL
static constexpr float DF = 0.7f;                                  // DAMP_FIELD
static constexpr int   NITER = 7;
#define SCAN_B 512
#define CHUNK 8192
#define MAXBUCK 512

__device__ inline unsigned packh2(float a, float b) {
    return (unsigned)__half_as_ushort(__float2half_rn(a)) |
           ((unsigned)__half_as_ushort(__float2half_rn(b)) << 16);
}
__device__ inline float unph_lo(unsigned u) {
    return __half2float(__ushort_as_half((unsigned short)(u & 0xFFFFu)));
}
__device__ inline float unph_hi(unsigned u) {
    return __half2float(__ushort_as_half((unsigned short)(u >> 16)));
}

// ---------------- build: per-(block,bucket) histogram ----------------

__global__ void bhist_kernel(const int* __restrict__ esrc, int* __restrict__ h,
                             int E, int nbuck, int nblk)
{
    __shared__ int cnt[MAXBUCK];
    int tid = threadIdx.x, blk = blockIdx.x;
    for (int b = tid; b < nbuck; b += blockDim.x) cnt[b] = 0;
    __syncthreads();
    int lo = blk * CHUNK, hi = min(E, lo + CHUNK);
    for (int i = lo + tid; i < hi; i += blockDim.x)
        atomicAdd(&cnt[esrc[i] >> 8], 1);
    __syncthreads();
    for (int b = tid; b < nbuck; b += blockDim.x)
        h[b * nblk + blk] = cnt[b];                 // bucket-major for scan
}

// ---------------- 2-level exclusive scan ----------------

__global__ void scan1_kernel(const int* __restrict__ in, int* __restrict__ excl,
                             int* __restrict__ blocksum, int n)
{
    __shared__ int sh[SCAN_B];
    int tid = threadIdx.x;
    int i = blockIdx.x * SCAN_B + tid;
    int v = (i < n) ? in[i] : 0;
    sh[tid] = v;
    __syncthreads();
    for (int off = 1; off < SCAN_B; off <<= 1) {
        int t = (tid >= off) ? sh[tid - off] : 0;
        __syncthreads();
        sh[tid] += t;
        __syncthreads();
    }
    if (i < n) excl[i] = sh[tid] - v;
    if (tid == SCAN_B - 1) blocksum[blockIdx.x] = sh[tid];
}

__global__ void scan2_kernel(int* __restrict__ blocksum, int nb)
{
    __shared__ int sh[512];
    int tid = threadIdx.x;
    int v = (tid < nb) ? blocksum[tid] : 0;
    sh[tid] = v;
    __syncthreads();
    for (int off = 1; off < 512; off <<= 1) {
        int t = (tid >= off) ? sh[tid - off] : 0;
        __syncthreads();
        sh[tid] += t;
        __syncthreads();
    }
    if (tid < nb) blocksum[tid] = sh[tid] - v;
}

__global__ void scan3_kernel(int* __restrict__ excl, const int* __restrict__ blocksum, int n)
{
    int i = blockIdx.x * SCAN_B + threadIdx.x;
    if (i < n) excl[i] += blocksum[blockIdx.x];
}

__global__ void bktptr_kernel(const int* __restrict__ hoff, int* __restrict__ bktptr,
                              int nbuck, int nblk, int E)
{
    int b = blockIdx.x * blockDim.x + threadIdx.x;
    if (b < nbuck) bktptr[b] = hoff[b * nblk];
    if (b == nbuck) bktptr[b] = E;
}

// ---------------- build: physics + single-stream 16B records ----------------
// matvec term: t = c1*mu_d - (w.mu_d)*w, w = sqrt(3*l5m*inv_r5)*vec_ij.
// E0 term: g*w with g = l3f*q_d*inv_r3 / sw  (sw >= 5e-4 since u >= 0.5).

__global__ void build_kernel(const int* __restrict__ esrc, const int* __restrict__ edst,
                             const float* __restrict__ dist, const float* __restrict__ vec,
                             const float* __restrict__ pol, const float* __restrict__ chg,
                             const int* __restrict__ hoff,
                             uint4* __restrict__ recs, int E, int nbuck, int nblk)
{
    __shared__ int cur[MAXBUCK];
    int tid = threadIdx.x, blk = blockIdx.x;
    for (int b = tid; b < nbuck; b += blockDim.x) cur[b] = hoff[b * nblk + blk];
    __syncthreads();
    int lo = blk * CHUNK, hi = min(E, lo + CHUNK);
    for (int i = lo + tid; i < hi; i += blockDim.x) {
        int s = esrc[i], d = edst[i];
        float r  = dist[i] * INV_B;
        float vx = vec[3*i+0] * INV_B;
        float vy = vec[3*i+1] * INV_B;
        float vz = vec[3*i+2] * INV_B;
        float ps = pol[s] * INV_B3;
        float pd = pol[d] * INV_B3;
        float r2 = r * r;
        float r3 = r2 * r;
        float u  = r3 * rsqrtf(ps * pd);
        float em = __expf(-DM * u);
        float l3m = 1.0f - em;
        float l5m = 1.0f - (1.0f + DM * u) * em;
        float inv_r3 = 1.0f / r3;
        float inv_r5 = inv_r3 / r2;
        float c1 = l3m * inv_r3;
        float sw = sqrtf(3.0f * l5m * inv_r5);
        float ec = (1.0f - __expf(-DF * u)) * chg[d] * inv_r3;
        float g  = ec / sw;
        int slot = atomicAdd(&cur[s >> 8], 1);      // LDS cursor
        uint4 rc;
        rc.x = (unsigned)(d | ((s & 255) << 20));
        rc.y = __float_as_uint(c1);
        rc.z = packh2(sw * vx, sw * vy);
        rc.w = packh2(sw * vz, g);
        recs[slot] = rc;                             // single 16B write stream/bucket
    }
}

// ---------------- iterate: bucket-centric, LDS accumulation ----------------

__global__ void e0b_kernel(const int* __restrict__ bktptr, const uint4* __restrict__ recs,
                           const float* __restrict__ pol,
                           float4* __restrict__ E0, float4* __restrict__ mu, int N)
{
    __shared__ float acc[256 * 3];
    int tid = threadIdx.x, b = blockIdx.x;
    for (int k = tid; k < 768; k += 256) acc[k] = 0.f;
    __syncthreads();
    int j0 = bktptr[b], j1 = bktptr[b + 1];
    for (int j = j0 + tid; j < j1; j += 256) {
        uint4 rc = recs[j];
        int lr = (int)(rc.x >> 20);
        float g  = unph_hi(rc.w);
        atomicAdd(&acc[lr*3+0], g * unph_lo(rc.z));
        atomicAdd(&acc[lr*3+1], g * unph_hi(rc.z));
        atomicAdd(&acc[lr*3+2], g * unph_lo(rc.w));
    }
    __syncthreads();
    int r = b * 256 + tid;
    if (r < N) {
        float ax = acc[tid*3], ay = acc[tid*3+1], az = acc[tid*3+2];
        E0[r] = make_float4(ax, ay, az, 0.f);
        float a = pol[r] * INV_B3;
        mu[r] = make_float4(a * ax, a * ay, a * az, 0.f);
    }
}

__global__ void mvb_kernel(const int* __restrict__ bktptr, const uint4* __restrict__ recs,
                           const float4* __restrict__ E0, const float* __restrict__ pol,
                           const float4* __restrict__ mu_in, float4* __restrict__ mu_out,
                           float* __restrict__ energy, int N, int final_iter)
{
    __shared__ float acc[256 * 3];
    int tid = threadIdx.x, b = blockIdx.x;
    for (int k = tid; k < 768; k += 256) acc[k] = 0.f;
    __syncthreads();
    int j0 = bktptr[b], j1 = bktptr[b + 1];
    for (int j = j0 + tid; j < j1; j += 256) {
        uint4 rc = recs[j];
        float4 m = mu_in[rc.x & 0xFFFFF];           // random 16B, L2-resident 1.6MB
        float c1 = __uint_as_float(rc.y);
        float wx = unph_lo(rc.z), wy = unph_hi(rc.z), wz = unph_lo(rc.w);
        float dot = wx * m.x + wy * m.y + wz * m.z;
        int lr = (int)(rc.x >> 20);
        atomicAdd(&acc[lr*3+0], c1 * m.x - dot * wx);
        atomicAdd(&acc[lr*3+1], c1 * m.y - dot * wy);
        atomicAdd(&acc[lr*3+2], c1 * m.z - dot * wz);
    }
    __syncthreads();
    int r = b * 256 + tid;
    if (r < N) {
        float4 e0 = E0[r];
        float a = pol[r] * INV_B3;
        float mx = a * (e0.x - acc[tid*3+0]);
        float my = a * (e0.y - acc[tid*3+1]);
        float mz = a * (e0.z - acc[tid*3+2]);
        mu_out[r] = make_float4(mx, my, mz, 0.f);
        if (final_iter)
            energy[r] = -0.5f * (mx * e0.x + my * e0.y + mz * e0.z);
    }
}

// ---------------- fallback (atomic path, tiny ws) ----------------

__global__ void fb_e0_kernel(const int* esrc, const int* edst, const float* dist,
                             const float* vec, const float* pol, const float* chg,
                             float4* E0, int E)
{
    int e = blockIdx.x * blockDim.x + threadIdx.x;
    if (e >= E) return;
    int s = esrc[e], d = edst[e];
    float r  = dist[e] * INV_B;
    float vx = vec[3*e+0]*INV_B, vy = vec[3*e+1]*INV_B, vz = vec[3*e+2]*INV_B;
    float r3 = r*r*r;
    float u  = r3 * rsqrtf(pol[s]*INV_B3 * pol[d]*INV_B3);
    float ec = (1.0f - __expf(-DF*u)) * chg[d] / r3;
    atomicAdd(&E0[s].x, ec*vx); atomicAdd(&E0[s].y, ec*vy); atomicAdd(&E0[s].z, ec*vz);
}

__global__ void fb_init_kernel(const float* pol, const float4* E0, float4* mu, float4* acc, int N)
{
    int i = blockIdx.x * blockDim.x + threadIdx.x;
    if (i >= N) return;
    float a = pol[i]*INV_B3; float4 e0 = E0[i];
    mu[i]  = make_float4(a*e0.x, a*e0.y, a*e0.z, 0.f);
    acc[i] = make_float4(0.f,0.f,0.f,0.f);
}

__global__ void fb_matvec_kernel(const int* esrc, const int* edst, const float* dist,
                                 const float* vec, const float* pol,
                                 const float4* mu, float4* acc, int E)
{
    int e = blockIdx.x * blockDim.x + threadIdx.x;
    if (e >= E) return;
    int s = esrc[e], d = edst[e];
    float r  = dist[e]*INV_B;
    float vx = vec[3*e+0]*INV_B, vy = vec[3*e+1]*INV_B, vz = vec[3*e+2]*INV_B;
    float r2 = r*r, r3 = r2*r;
    float u  = r3 * rsqrtf(pol[s]*INV_B3 * pol[d]*INV_B3);
    float em = __expf(-DM*u);
    float c1 = (1.0f - em) / r3;
    float c2 = 3.0f * (1.0f - (1.0f + DM*u)*em) / (r3*r2);
    float4 m = mu[d];
    float k = c2 * (vx*m.x + vy*m.y + vz*m.z);
    atomicAdd(&acc[s].x, c1*m.x - k*vx);
    atomicAdd(&acc[s].y, c1*m.y - k*vy);
    atomicAdd(&acc[s].z, c1*m.z - k*vz);
}

__global__ void fb_update_kernel(const float* pol, const float4* E0, float4* acc,
                                 float4* mu, float* energy, int N, int final_iter)
{
    int i = blockIdx.x * blockDim.x + threadIdx.x;
    if (i >= N) return;
    float a = pol[i]*INV_B3; float4 e0 = E0[i]; float4 ac = acc[i];
    float mx = a*(e0.x-ac.x), my = a*(e0.y-ac.y), mz = a*(e0.z-ac.z);
    mu[i]  = make_float4(mx,my,mz,0.f);
    acc[i] = make_float4(0.f,0.f,0.f,0.f);
    if (final_iter) energy[i] = -0.5f*(mx*e0.x + my*e0.y + mz*e0.z);
}

// ---------------- launch ----------------

static inline size_t align_up(size_t x, size_t a) { return (x + a - 1) & ~(a - 1); }

extern "C" void kernel_launch(void* const* d_in, const int* in_sizes, int n_in,
                              void* d_out, int out_size, void* d_ws, size_t ws_size,
                              hipStream_t stream)
{
    // inputs: species, edge_src, edge_dst, distances, vec, polarisability, charges
    const int*   esrc = (const int*)  d_in[1];
    const int*   edst = (const int*)  d_in[2];
    const float* dist = (const float*)d_in[3];
    const float* vec  = (const float*)d_in[4];
    const float* pol  = (const float*)d_in[5];
    const float* chg  = (const float*)d_in[6];
    const int E = in_sizes[1];
    const int N = in_sizes[5];
    float* out = (float*)d_out;

    const int nbuck = (N + 255) >> 8;                  // 391 for N=100k
    const int nblk  = (E + CHUNK - 1) / CHUNK;         // 392 for E=3.2M
    const int nScan = nbuck * nblk;                    // ~153k
    const int g1    = (nScan + SCAN_B - 1) / SCAN_B;   // ~300

    // workspace layout (~57 MB)
    char* ws = (char*)d_ws;
    size_t off = 0;
    auto carve = [&](size_t bytes) { size_t o = off; off = align_up(off + bytes, 256); return o; };
    size_t o_h      = carve((size_t)nScan * 4);
    size_t o_hoff   = carve((size_t)nScan * 4);
    size_t o_bsum   = carve(512 * 4);
    size_t o_bkt    = carve((size_t)(nbuck + 1) * 4);
    size_t o_E0     = carve((size_t)N * 16);
    size_t o_mua    = carve((size_t)N * 16);
    size_t o_mub    = carve((size_t)N * 16);
    size_t o_recs   = carve((size_t)E * 16);
    size_t need = off;

    bool ok = (ws_size >= need) && (nbuck <= MAXBUCK) && (g1 <= 512) &&
              (nbuck >= 1) && (N < (1 << 20));

    if (ok) {
        int*    h      = (int*)   (ws + o_h);
        int*    hoff   = (int*)   (ws + o_hoff);
        int*    bsum   = (int*)   (ws + o_bsum);
        int*    bktptr = (int*)   (ws + o_bkt);
        float4* E0     = (float4*)(ws + o_E0);
        float4* mu_a   = (float4*)(ws + o_mua);
        float4* mu_b   = (float4*)(ws + o_mub);
        uint4*  recs   = (uint4*) (ws + o_recs);

        bhist_kernel<<<nblk, 256, 0, stream>>>(esrc, h, E, nbuck, nblk);
        scan1_kernel<<<g1, SCAN_B, 0, stream>>>(h, hoff, bsum, nScan);
        scan2_kernel<<<1, 512, 0, stream>>>(bsum, g1);
        scan3_kernel<<<g1, SCAN_B, 0, stream>>>(hoff, bsum, nScan);
        bktptr_kernel<<<(nbuck + 256) / 256, 256, 0, stream>>>(hoff, bktptr, nbuck, nblk, E);
        build_kernel<<<nblk, 256, 0, stream>>>(esrc, edst, dist, vec, pol, chg,
                                               hoff, recs, E, nbuck, nblk);

        e0b_kernel<<<nbuck, 256, 0, stream>>>(bktptr, recs, pol, E0, mu_a, N);

        float4* min_ = mu_a; float4* mout_ = mu_b;
        for (int it = 0; it < NITER; ++it) {
            mvb_kernel<<<nbuck, 256, 0, stream>>>(bktptr, recs, E0, pol,
                                                  min_, mout_, out, N, it == NITER - 1);
            float4* t = min_; min_ = mout_; mout_ = t;
        }
    } else {
        // fallback: atomic scatter path (needs 48B/node)
        float4* E0  = (float4*)(ws);
        float4* mu  = (float4*)(ws + (size_t)N * 16);
        float4* acc = (float4*)(ws + (size_t)N * 32);
        const int EB = 256, NB = 256;
        const int EG = (E + EB - 1) / EB;
        const int NG = (N + NB - 1) / NB;
        hipMemsetAsync(E0, 0, (size_t)N * 16, stream);
        fb_e0_kernel<<<EG, EB, 0, stream>>>(esrc, edst, dist, vec, pol, chg, E0, E);
        fb_init_kernel<<<NG, NB, 0, stream>>>(pol, E0, mu, acc, N);
        for (int it = 0; it < NITER; ++it) {
            fb_matvec_kernel<<<EG, EB, 0, stream>>>(esrc, edst, dist, vec, pol, mu, acc, E);
            fb_update_kernel<<<NG, NB, 0, stream>>>(pol, E0, acc, mu, out, N, it == NITER - 1);
        }
    }
}

// Round 6
// 336.954 us; speedup vs baseline: 2.4496x; 1.8572x over previous
//
#include <hip/hip_runtime.h>
#include <hip/hip_fp16.h>

// Polarisation solver v6: padded bucket build (no false sharing) + per-bucket
// counting sort to full row-CSR + atomic-free row-gather Jacobi iterations.
// record (16B) = {dst|(localrow<<20), c1 f32, wx|wy f16x2, wz|g f16x2}.
// Dummy pad records are all-zero (c1==0 flags them; they contribute nothing).

static constexpr float INV_B  = 1.0f / 0.52917721067f;            // 1/BOHR
static constexpr float INV_B3 = INV_B * INV_B * INV_B;            // 1/BOHR^3
static constexpr float DM = 0.39f;                                 // DAMP_MUTUAL
static constexpr float DF = 0.7f;                                  // DAMP_FIELD
static constexpr int   NITER = 7;
#define SCAN_B 512
#define CHUNK 8192
#define MAXBUCK 512

__device__ inline unsigned packh2(float a, float b) {
    return (unsigned)__half_as_ushort(__float2half_rn(a)) |
           ((unsigned)__half_as_ushort(__float2half_rn(b)) << 16);
}
__device__ inline float unph_lo(unsigned u) {
    return __half2float(__ushort_as_half((unsigned short)(u & 0xFFFFu)));
}
__device__ inline float unph_hi(unsigned u) {
    return __half2float(__ushort_as_half((unsigned short)(u >> 16)));
}

// ---------------- build: per-(block,bucket) histogram (raw + padded) ----------------

__global__ void bhist_kernel(const int* __restrict__ esrc, int* __restrict__ hraw,
                             int* __restrict__ hpad, int E, int nbuck, int nblk)
{
    __shared__ int cnt[MAXBUCK];
    int tid = threadIdx.x, blk = blockIdx.x;
    for (int b = tid; b < nbuck; b += blockDim.x) cnt[b] = 0;
    __syncthreads();
    int lo = blk * CHUNK, hi = min(E, lo + CHUNK);
    for (int i = lo + tid; i < hi; i += blockDim.x)
        atomicAdd(&cnt[esrc[i] >> 8], 1);
    __syncthreads();
    for (int b = tid; b < nbuck; b += blockDim.x) {
        int c = cnt[b];
        hraw[b * nblk + blk] = c;                  // bucket-major
        hpad[b * nblk + blk] = (c + 3) & ~3;       // 64B-aligned runs (4 recs/line)
    }
}

// ---------------- 2-level exclusive scan ----------------

__global__ void scan1_kernel(const int* __restrict__ in, int* __restrict__ excl,
                             int* __restrict__ blocksum, int n)
{
    __shared__ int sh[SCAN_B];
    int tid = threadIdx.x;
    int i = blockIdx.x * SCAN_B + tid;
    int v = (i < n) ? in[i] : 0;
    sh[tid] = v;
    __syncthreads();
    for (int off = 1; off < SCAN_B; off <<= 1) {
        int t = (tid >= off) ? sh[tid - off] : 0;
        __syncthreads();
        sh[tid] += t;
        __syncthreads();
    }
    if (i < n) excl[i] = sh[tid] - v;
    if (tid == SCAN_B - 1) blocksum[blockIdx.x] = sh[tid];
}

__global__ void scan2_kernel(int* __restrict__ blocksum, int nb)
{
    __shared__ int sh[512];
    int tid = threadIdx.x;
    int v = (tid < nb) ? blocksum[tid] : 0;
    sh[tid] = v;
    __syncthreads();
    for (int off = 1; off < 512; off <<= 1) {
        int t = (tid >= off) ? sh[tid - off] : 0;
        __syncthreads();
        sh[tid] += t;
        __syncthreads();
    }
    if (tid < nb) blocksum[tid] = sh[tid] - v;
}

__global__ void scan3_kernel(int* __restrict__ excl, const int* __restrict__ blocksum, int n)
{
    int i = blockIdx.x * SCAN_B + threadIdx.x;
    if (i < n) excl[i] += blocksum[blockIdx.x];
}

__global__ void bktptr_kernel(const int* __restrict__ hoffpad, const int* __restrict__ hpad,
                              int* __restrict__ bktptr, int nbuck, int nblk, int nScan)
{
    int b = blockIdx.x * blockDim.x + threadIdx.x;
    if (b < nbuck) bktptr[b] = hoffpad[b * nblk];
    if (b == nbuck) bktptr[b] = hoffpad[nScan - 1] + hpad[nScan - 1];
}

// ---------------- build: physics + padded single-stream 16B records ----------------
// matvec term: t = c1*mu_d - (w.mu_d)*w, w = sqrt(3*l5m*inv_r5)*vec_ij.
// E0 term: g*w with g = l3f*q_d*inv_r3 / sw.

__global__ void build_kernel(const int* __restrict__ esrc, const int* __restrict__ edst,
                             const float* __restrict__ dist, const float* __restrict__ vec,
                             const float* __restrict__ pol, const float* __restrict__ chg,
                             const int* __restrict__ hoffpad, const int* __restrict__ hpad,
                             uint4* __restrict__ recs, int E, int nbuck, int nblk)
{
    __shared__ int cur[MAXBUCK];
    int tid = threadIdx.x, blk = blockIdx.x;
    for (int b = tid; b < nbuck; b += blockDim.x) cur[b] = hoffpad[b * nblk + blk];
    __syncthreads();
    int lo = blk * CHUNK, hi = min(E, lo + CHUNK);
    for (int i = lo + tid; i < hi; i += blockDim.x) {
        int s = esrc[i], d = edst[i];
        float r  = dist[i] * INV_B;
        float vx = vec[3*i+0] * INV_B;
        float vy = vec[3*i+1] * INV_B;
        float vz = vec[3*i+2] * INV_B;
        float ps = pol[s] * INV_B3;
        float pd = pol[d] * INV_B3;
        float r2 = r * r;
        float r3 = r2 * r;
        float u  = r3 * rsqrtf(ps * pd);
        float em = __expf(-DM * u);
        float l3m = 1.0f - em;
        float l5m = 1.0f - (1.0f + DM * u) * em;
        float inv_r3 = 1.0f / r3;
        float inv_r5 = inv_r3 / r2;
        float c1 = l3m * inv_r3;                    // >= ~1.2e-4 always (nonzero flag)
        float sw = sqrtf(3.0f * l5m * inv_r5);
        float ec = (1.0f - __expf(-DF * u)) * chg[d] * inv_r3;
        float g  = ec / sw;
        int slot = atomicAdd(&cur[s >> 8], 1);      // LDS cursor
        uint4 rc;
        rc.x = (unsigned)(d | ((s & 255) << 20));
        rc.y = __float_as_uint(c1);
        rc.z = packh2(sw * vx, sw * vy);
        rc.w = packh2(sw * vz, g);
        recs[slot] = rc;
    }
    __syncthreads();
    // fill pad slots with zero records (c1==0 marks dummy; harmless everywhere)
    for (int b = tid; b < nbuck; b += blockDim.x) {
        int base = hoffpad[b * nblk + blk];
        int end  = base + hpad[b * nblk + blk];
        for (int s = cur[b]; s < end; ++s) recs[s] = make_uint4(0, 0, 0, 0);
    }
}

// ---------------- per-bucket counting sort to tight row-CSR ----------------

__global__ void sort_kernel(const int* __restrict__ bktptr, const int* __restrict__ hoffraw,
                            int nblk, const uint4* __restrict__ recs_raw,
                            uint4* __restrict__ recs_srt,
                            int* __restrict__ rowbeg, int* __restrict__ rowend, int N)
{
    __shared__ int hist[256];
    __shared__ int scn[256];
    __shared__ int cur[256];
    int tid = threadIdx.x, b = blockIdx.x;
    int j0 = bktptr[b], j1 = bktptr[b + 1];
    int tight0 = hoffraw[b * nblk];                 // tight start of this bucket
    hist[tid] = 0;
    __syncthreads();
    for (int j = j0 + tid; j < j1; j += 256) {
        uint4 rc = recs_raw[j];
        if (rc.y) atomicAdd(&hist[rc.x >> 20], 1);
    }
    __syncthreads();
    int cnt = hist[tid];
    scn[tid] = cnt;
    __syncthreads();
    for (int off = 1; off < 256; off <<= 1) {
        int t = (tid >= off) ? scn[tid - off] : 0;
        __syncthreads();
        scn[tid] += t;
        __syncthreads();
    }
    int beg = tight0 + scn[tid] - cnt;              // exclusive
    cur[tid] = beg;
    int row = b * 256 + tid;
    if (row < N) { rowbeg[row] = beg; rowend[row] = beg + cnt; }
    __syncthreads();
    for (int j = j0 + tid; j < j1; j += 256) {
        uint4 rc = recs_raw[j];
        if (rc.y) {
            int slot = atomicAdd(&cur[rc.x >> 20], 1);
            recs_srt[slot] = rc;                    // random write within L2-resident window
        }
    }
}

// ---------------- iterate: row-CSR gather, 16 lanes/row, no atomics ----------------

__global__ void e0g_kernel(const int* __restrict__ rowbeg, const int* __restrict__ rowend,
                           const uint4* __restrict__ recs, const float* __restrict__ pol,
                           float4* __restrict__ E0, float4* __restrict__ mu, int N)
{
    int tid  = threadIdx.x;
    int lane = tid & 15;
    int row  = (blockIdx.x * blockDim.x + tid) >> 4;
    if (row >= N) return;
    int r0 = rowbeg[row], r1 = rowend[row];
    float sx = 0.f, sy = 0.f, sz = 0.f;
    for (int j = r0 + lane; j < r1; j += 16) {
        uint4 rc = recs[j];
        float g = unph_hi(rc.w);
        sx += g * unph_lo(rc.z);
        sy += g * unph_hi(rc.z);
        sz += g * unph_lo(rc.w);
    }
    for (int m = 8; m >= 1; m >>= 1) {
        sx += __shfl_xor(sx, m);
        sy += __shfl_xor(sy, m);
        sz += __shfl_xor(sz, m);
    }
    if (lane == 0) {
        E0[row] = make_float4(sx, sy, sz, 0.f);
        float a = pol[row] * INV_B3;
        mu[row] = make_float4(a * sx, a * sy, a * sz, 0.f);
    }
}

__global__ void mvg_kernel(const int* __restrict__ rowbeg, const int* __restrict__ rowend,
                           const uint4* __restrict__ recs, const float4* __restrict__ E0,
                           const float* __restrict__ pol,
                           const float4* __restrict__ mu_in, float4* __restrict__ mu_out,
                           float* __restrict__ energy, int N, int final_iter)
{
    int tid  = threadIdx.x;
    int lane = tid & 15;
    int row  = (blockIdx.x * blockDim.x + tid) >> 4;
    if (row >= N) return;
    int r0 = rowbeg[row], r1 = rowend[row];
    float ax = 0.f, ay = 0.f, az = 0.f;
    for (int j = r0 + lane; j < r1; j += 16) {
        uint4 rc = recs[j];
        float4 m = mu_in[rc.x & 0xFFFFF];           // random 16B, L2-resident 1.6MB
        float c1 = __uint_as_float(rc.y);
        float wx = unph_lo(rc.z), wy = unph_hi(rc.z), wz = unph_lo(rc.w);
        float dot = wx * m.x + wy * m.y + wz * m.z;
        ax += c1 * m.x - dot * wx;
        ay += c1 * m.y - dot * wy;
        az += c1 * m.z - dot * wz;
    }
    for (int msk = 8; msk >= 1; msk >>= 1) {
        ax += __shfl_xor(ax, msk);
        ay += __shfl_xor(ay, msk);
        az += __shfl_xor(az, msk);
    }
    if (lane == 0) {
        float4 e0 = E0[row];
        float a = pol[row] * INV_B3;
        float mx = a * (e0.x - ax);
        float my = a * (e0.y - ay);
        float mz = a * (e0.z - az);
        mu_out[row] = make_float4(mx, my, mz, 0.f);
        if (final_iter)
            energy[row] = -0.5f * (mx * e0.x + my * e0.y + mz * e0.z);
    }
}

// ---------------- middle path: bucket iterate on padded recs (v5) ----------------

__global__ void e0b_kernel(const int* __restrict__ bktptr, const uint4* __restrict__ recs,
                           const float* __restrict__ pol,
                           float4* __restrict__ E0, float4* __restrict__ mu, int N)
{
    __shared__ float acc[256 * 3];
    int tid = threadIdx.x, b = blockIdx.x;
    for (int k = tid; k < 768; k += 256) acc[k] = 0.f;
    __syncthreads();
    int j0 = bktptr[b], j1 = bktptr[b + 1];
    for (int j = j0 + tid; j < j1; j += 256) {
        uint4 rc = recs[j];
        int lr = (int)(rc.x >> 20) & 255;
        float g = unph_hi(rc.w);
        atomicAdd(&acc[lr*3+0], g * unph_lo(rc.z));
        atomicAdd(&acc[lr*3+1], g * unph_hi(rc.z));
        atomicAdd(&acc[lr*3+2], g * unph_lo(rc.w));
    }
    __syncthreads();
    int r = b * 256 + tid;
    if (r < N) {
        float ax = acc[tid*3], ay = acc[tid*3+1], az = acc[tid*3+2];
        E0[r] = make_float4(ax, ay, az, 0.f);
        float a = pol[r] * INV_B3;
        mu[r] = make_float4(a * ax, a * ay, a * az, 0.f);
    }
}

__global__ void mvb_kernel(const int* __restrict__ bktptr, const uint4* __restrict__ recs,
                           const float4* __restrict__ E0, const float* __restrict__ pol,
                           const float4* __restrict__ mu_in, float4* __restrict__ mu_out,
                           float* __restrict__ energy, int N, int final_iter)
{
    __shared__ float acc[256 * 3];
    int tid = threadIdx.x, b = blockIdx.x;
    for (int k = tid; k < 768; k += 256) acc[k] = 0.f;
    __syncthreads();
    int j0 = bktptr[b], j1 = bktptr[b + 1];
    for (int j = j0 + tid; j < j1; j += 256) {
        uint4 rc = recs[j];
        float4 m = mu_in[rc.x & 0xFFFFF];
        float c1 = __uint_as_float(rc.y);
        float wx = unph_lo(rc.z), wy = unph_hi(rc.z), wz = unph_lo(rc.w);
        float dot = wx * m.x + wy * m.y + wz * m.z;
        int lr = (int)(rc.x >> 20) & 255;
        atomicAdd(&acc[lr*3+0], c1 * m.x - dot * wx);
        atomicAdd(&acc[lr*3+1], c1 * m.y - dot * wy);
        atomicAdd(&acc[lr*3+2], c1 * m.z - dot * wz);
    }
    __syncthreads();
    int r = b * 256 + tid;
    if (r < N) {
        float4 e0 = E0[r];
        float a = pol[r] * INV_B3;
        float mx = a * (e0.x - acc[tid*3+0]);
        float my = a * (e0.y - acc[tid*3+1]);
        float mz = a * (e0.z - acc[tid*3+2]);
        mu_out[r] = make_float4(mx, my, mz, 0.f);
        if (final_iter)
            energy[r] = -0.5f * (mx * e0.x + my * e0.y + mz * e0.z);
    }
}

// ---------------- fallback (atomic path, tiny ws) ----------------

__global__ void fb_e0_kernel(const int* esrc, const int* edst, const float* dist,
                             const float* vec, const float* pol, const float* chg,
                             float4* E0, int E)
{
    int e = blockIdx.x * blockDim.x + threadIdx.x;
    if (e >= E) return;
    int s = esrc[e], d = edst[e];
    float r  = dist[e] * INV_B;
    float vx = vec[3*e+0]*INV_B, vy = vec[3*e+1]*INV_B, vz = vec[3*e+2]*INV_B;
    float r3 = r*r*r;
    float u  = r3 * rsqrtf(pol[s]*INV_B3 * pol[d]*INV_B3);
    float ec = (1.0f - __expf(-DF*u)) * chg[d] / r3;
    atomicAdd(&E0[s].x, ec*vx); atomicAdd(&E0[s].y, ec*vy); atomicAdd(&E0[s].z, ec*vz);
}

__global__ void fb_init_kernel(const float* pol, const float4* E0, float4* mu, float4* acc, int N)
{
    int i = blockIdx.x * blockDim.x + threadIdx.x;
    if (i >= N) return;
    float a = pol[i]*INV_B3; float4 e0 = E0[i];
    mu[i]  = make_float4(a*e0.x, a*e0.y, a*e0.z, 0.f);
    acc[i] = make_float4(0.f,0.f,0.f,0.f);
}

__global__ void fb_matvec_kernel(const int* esrc, const int* edst, const float* dist,
                                 const float* vec, const float* pol,
                                 const float4* mu, float4* acc, int E)
{
    int e = blockIdx.x * blockDim.x + threadIdx.x;
    if (e >= E) return;
    int s = esrc[e], d = edst[e];
    float r  = dist[e]*INV_B;
    float vx = vec[3*e+0]*INV_B, vy = vec[3*e+1]*INV_B, vz = vec[3*e+2]*INV_B;
    float r2 = r*r, r3 = r2*r;
    float u  = r3 * rsqrtf(pol[s]*INV_B3 * pol[d]*INV_B3);
    float em = __expf(-DM*u);
    float c1 = (1.0f - em) / r3;
    float c2 = 3.0f * (1.0f - (1.0f + DM*u)*em) / (r3*r2);
    float4 m = mu[d];
    float k = c2 * (vx*m.x + vy*m.y + vz*m.z);
    atomicAdd(&acc[s].x, c1*m.x - k*vx);
    atomicAdd(&acc[s].y, c1*m.y - k*vy);
    atomicAdd(&acc[s].z, c1*m.z - k*vz);
}

__global__ void fb_update_kernel(const float* pol, const float4* E0, float4* acc,
                                 float4* mu, float* energy, int N, int final_iter)
{
    int i = blockIdx.x * blockDim.x + threadIdx.x;
    if (i >= N) return;
    float a = pol[i]*INV_B3; float4 e0 = E0[i]; float4 ac = acc[i];
    float mx = a*(e0.x-ac.x), my = a*(e0.y-ac.y), mz = a*(e0.z-ac.z);
    mu[i]  = make_float4(mx,my,mz,0.f);
    acc[i] = make_float4(0.f,0.f,0.f,0.f);
    if (final_iter) energy[i] = -0.5f*(mx*e0.x + my*e0.y + mz*e0.z);
}

// ---------------- launch ----------------

static inline size_t align_up(size_t x, size_t a) { return (x + a - 1) & ~(a - 1); }

extern "C" void kernel_launch(void* const* d_in, const int* in_sizes, int n_in,
                              void* d_out, int out_size, void* d_ws, size_t ws_size,
                              hipStream_t stream)
{
    // inputs: species, edge_src, edge_dst, distances, vec, polarisability, charges
    const int*   esrc = (const int*)  d_in[1];
    const int*   edst = (const int*)  d_in[2];
    const float* dist = (const float*)d_in[3];
    const float* vec  = (const float*)d_in[4];
    const float* pol  = (const float*)d_in[5];
    const float* chg  = (const float*)d_in[6];
    const int E = in_sizes[1];
    const int N = in_sizes[5];
    float* out = (float*)d_out;

    const int nbuck = (N + 255) >> 8;                  // 391
    const int nblk  = (E + CHUNK - 1) / CHUNK;         // 392
    const int nScan = nbuck * nblk;                    // ~153k
    const int g1    = (nScan + SCAN_B - 1) / SCAN_B;   // ~300
    const size_t Epad = (size_t)E + 3u * (size_t)nScan;

    // workspace layout: middle-path arrays first, sort-path extras last
    char* ws = (char*)d_ws;
    size_t off = 0;
    auto carve = [&](size_t bytes) { size_t o = off; off = align_up(off + bytes, 256); return o; };
    size_t o_hpad    = carve((size_t)nScan * 4);
    size_t o_hoffpad = carve((size_t)nScan * 4);
    size_t o_bsum1   = carve(512 * 4);
    size_t o_bkt     = carve((size_t)(nbuck + 1) * 4);
    size_t o_E0      = carve((size_t)N * 16);
    size_t o_mua     = carve((size_t)N * 16);
    size_t o_mub     = carve((size_t)N * 16);
    size_t o_hraw    = carve((size_t)nScan * 4);
    size_t o_recsraw = carve(Epad * 16);
    size_t need_mid  = off;
    size_t o_hoffraw = carve((size_t)nScan * 4);
    size_t o_bsum2   = carve(512 * 4);
    size_t o_rowbeg  = carve((size_t)N * 4);
    size_t o_rowend  = carve((size_t)N * 4);
    size_t o_recssrt = carve((size_t)E * 16);
    size_t need_sort = off;

    bool shape_ok = (nbuck <= MAXBUCK) && (g1 <= 512) && (nbuck >= 1) && (N < (1 << 20));
    bool ok_sort = shape_ok && (ws_size >= need_sort);
    bool ok_mid  = shape_ok && (ws_size >= need_mid);

    if (ok_sort || ok_mid) {
        int*    hpad    = (int*)   (ws + o_hpad);
        int*    hoffpad = (int*)   (ws + o_hoffpad);
        int*    bsum1   = (int*)   (ws + o_bsum1);
        int*    bktptr  = (int*)   (ws + o_bkt);
        float4* E0      = (float4*)(ws + o_E0);
        float4* mu_a    = (float4*)(ws + o_mua);
        float4* mu_b    = (float4*)(ws + o_mub);
        int*    hraw    = (int*)   (ws + o_hraw);
        uint4*  recsraw = (uint4*) (ws + o_recsraw);

        bhist_kernel<<<nblk, 256, 0, stream>>>(esrc, hraw, hpad, E, nbuck, nblk);
        scan1_kernel<<<g1, SCAN_B, 0, stream>>>(hpad, hoffpad, bsum1, nScan);
        scan2_kernel<<<1, 512, 0, stream>>>(bsum1, g1);
        scan3_kernel<<<g1, SCAN_B, 0, stream>>>(hoffpad, bsum1, nScan);
        bktptr_kernel<<<(nbuck + 256) / 256, 256, 0, stream>>>(hoffpad, hpad, bktptr,
                                                               nbuck, nblk, nScan);
        build_kernel<<<nblk, 256, 0, stream>>>(esrc, edst, dist, vec, pol, chg,
                                               hoffpad, hpad, recsraw, E, nbuck, nblk);

        if (ok_sort) {
            int*   hoffraw = (int*)  (ws + o_hoffraw);
            int*   bsum2   = (int*)  (ws + o_bsum2);
            int*   rowbeg  = (int*)  (ws + o_rowbeg);
            int*   rowend  = (int*)  (ws + o_rowend);
            uint4* recssrt = (uint4*)(ws + o_recssrt);

            scan1_kernel<<<g1, SCAN_B, 0, stream>>>(hraw, hoffraw, bsum2, nScan);
            scan2_kernel<<<1, 512, 0, stream>>>(bsum2, g1);
            scan3_kernel<<<g1, SCAN_B, 0, stream>>>(hoffraw, bsum2, nScan);
            sort_kernel<<<nbuck, 256, 0, stream>>>(bktptr, hoffraw, nblk,
                                                   recsraw, recssrt, rowbeg, rowend, N);

            const int NG16 = (N + 15) / 16;
            e0g_kernel<<<NG16, 256, 0, stream>>>(rowbeg, rowend, recssrt, pol, E0, mu_a, N);
            float4* min_ = mu_a; float4* mout_ = mu_b;
            for (int it = 0; it < NITER; ++it) {
                mvg_kernel<<<NG16, 256, 0, stream>>>(rowbeg, rowend, recssrt, E0, pol,
                                                     min_, mout_, out, N, it == NITER - 1);
                float4* t = min_; min_ = mout_; mout_ = t;
            }
        } else {
            e0b_kernel<<<nbuck, 256, 0, stream>>>(bktptr, recsraw, pol, E0, mu_a, N);
            float4* min_ = mu_a; float4* mout_ = mu_b;
            for (int it = 0; it < NITER; ++it) {
                mvb_kernel<<<nbuck, 256, 0, stream>>>(bktptr, recsraw, E0, pol,
                                                      min_, mout_, out, N, it == NITER - 1);
                float4* t = min_; min_ = mout_; mout_ = t;
            }
        }
    } else {
        // fallback: atomic scatter path (needs 48B/node)
        float4* E0  = (float4*)(ws);
        float4* mu  = (float4*)(ws + (size_t)N * 16);
        float4* acc = (float4*)(ws + (size_t)N * 32);
        const int EB = 256, NB = 256;
        const int EG = (E + EB - 1) / EB;
        const int NG = (N + NB - 1) / NB;
        hipMemsetAsync(E0, 0, (size_t)N * 16, stream);
        fb_e0_kernel<<<EG, EB, 0, stream>>>(esrc, edst, dist, vec, pol, chg, E0, E);
        fb_init_kernel<<<NG, NB, 0, stream>>>(pol, E0, mu, acc, N);
        for (int it = 0; it < NITER; ++it) {
            fb_matvec_kernel<<<EG, EB, 0, stream>>>(esrc, edst, dist, vec, pol, mu, acc, E);
            fb_update_kernel<<<NG, NB, 0, stream>>>(pol, E0, acc, mu, out, N, it == NITER - 1);
        }
    }
}

// Round 7
// 336.602 us; speedup vs baseline: 2.4521x; 1.0010x over previous
//
#include <hip/hip_runtime.h>
#include <hip/hip_fp16.h>

// Polarisation solver v7: 128B-padded bucket build at high occupancy (1024-thr
// blocks) + per-bucket counting sort emitting compact 12B records + atomic-free
// row-gather Jacobi iterations.
// raw record (16B) = {dst|(localrow<<20), c1 f32, wx|wy f16x2, wz|g f16x2}.
// sorted record (12B) = {dst|(lr<<20), c1|wx f16x2, wy|wz f16x2}; g in side array.
// Dummy pad records are all-zero (c1==0 flags them).

static constexpr float INV_B  = 1.0f / 0.52917721067f;            // 1/BOHR
static constexpr float INV_B3 = INV_B * INV_B * INV_B;            // 1/BOHR^3
static constexpr float DM = 0.39f;                                 // DAMP_MUTUAL
static constexpr float DF = 0.7f;                                  // DAMP_FIELD
static constexpr int   NITER = 7;
#define SCAN_B 512
#define CHUNK 16384
#define BUILD_T 1024
#define MAXBUCK 512

__device__ inline unsigned packh2(float a, float b) {
    return (unsigned)__half_as_ushort(__float2half_rn(a)) |
           ((unsigned)__half_as_ushort(__float2half_rn(b)) << 16);
}
__device__ inline float unph_lo(unsigned u) {
    return __half2float(__ushort_as_half((unsigned short)(u & 0xFFFFu)));
}
__device__ inline float unph_hi(unsigned u) {
    return __half2float(__ushort_as_half((unsigned short)(u >> 16)));
}

// ---------------- build: per-(block,bucket) histogram (raw + padded) ----------------

__global__ void bhist_kernel(const int* __restrict__ esrc, int* __restrict__ hraw,
                             int* __restrict__ hpad, int E, int nbuck, int nblk)
{
    __shared__ int cnt[MAXBUCK];
    int tid = threadIdx.x, blk = blockIdx.x;
    for (int b = tid; b < nbuck; b += blockDim.x) cnt[b] = 0;
    __syncthreads();
    int lo = blk * CHUNK, hi = min(E, lo + CHUNK);
    for (int i = lo + tid; i < hi; i += blockDim.x)
        atomicAdd(&cnt[esrc[i] >> 8], 1);
    __syncthreads();
    for (int b = tid; b < nbuck; b += blockDim.x) {
        int c = cnt[b];
        hraw[b * nblk + blk] = c;                  // bucket-major
        hpad[b * nblk + blk] = (c + 7) & ~7;       // 128B-aligned runs (8 recs/line-pair)
    }
}

// ---------------- 2-level exclusive scan ----------------

__global__ void scan1_kernel(const int* __restrict__ in, int* __restrict__ excl,
                             int* __restrict__ blocksum, int n)
{
    __shared__ int sh[SCAN_B];
    int tid = threadIdx.x;
    int i = blockIdx.x * SCAN_B + tid;
    int v = (i < n) ? in[i] : 0;
    sh[tid] = v;
    __syncthreads();
    for (int off = 1; off < SCAN_B; off <<= 1) {
        int t = (tid >= off) ? sh[tid - off] : 0;
        __syncthreads();
        sh[tid] += t;
        __syncthreads();
    }
    if (i < n) excl[i] = sh[tid] - v;
    if (tid == SCAN_B - 1) blocksum[blockIdx.x] = sh[tid];
}

__global__ void scan2_kernel(int* __restrict__ blocksum, int nb)
{
    __shared__ int sh[512];
    int tid = threadIdx.x;
    int v = (tid < nb) ? blocksum[tid] : 0;
    sh[tid] = v;
    __syncthreads();
    for (int off = 1; off < 512; off <<= 1) {
        int t = (tid >= off) ? sh[tid - off] : 0;
        __syncthreads();
        sh[tid] += t;
        __syncthreads();
    }
    if (tid < nb) blocksum[tid] = sh[tid] - v;
}

__global__ void scan3_kernel(int* __restrict__ excl, const int* __restrict__ blocksum, int n)
{
    int i = blockIdx.x * SCAN_B + threadIdx.x;
    if (i < n) excl[i] += blocksum[blockIdx.x];
}

__global__ void bktptr_kernel(const int* __restrict__ hoffpad, const int* __restrict__ hpad,
                              int* __restrict__ bktptr, int nbuck, int nblk, int nScan)
{
    int b = blockIdx.x * blockDim.x + threadIdx.x;
    if (b < nbuck) bktptr[b] = hoffpad[b * nblk];
    if (b == nbuck) bktptr[b] = hoffpad[nScan - 1] + hpad[nScan - 1];
}

// ---------------- build: physics + 128B-padded single-stream 16B records ----------------
// matvec term: t = c1*mu_d - (w.mu_d)*w, w = sqrt(3*l5m*inv_r5)*vec_ij.
// E0 term: g*w with g = l3f*q_d*inv_r3 / sw.

__global__ void build_kernel(const int* __restrict__ esrc, const int* __restrict__ edst,
                             const float* __restrict__ dist, const float* __restrict__ vec,
                             const float* __restrict__ pol, const float* __restrict__ chg,
                             const int* __restrict__ hoffpad, const int* __restrict__ hpad,
                             uint4* __restrict__ recs, int E, int nbuck, int nblk)
{
    __shared__ int cur[MAXBUCK];
    int tid = threadIdx.x, blk = blockIdx.x;
    for (int b = tid; b < nbuck; b += blockDim.x) cur[b] = hoffpad[b * nblk + blk];
    __syncthreads();
    int lo = blk * CHUNK, hi = min(E, lo + CHUNK);
    for (int i = lo + tid; i < hi; i += blockDim.x) {
        int s = esrc[i], d = edst[i];
        float r  = dist[i] * INV_B;
        float vx = vec[3*i+0] * INV_B;
        float vy = vec[3*i+1] * INV_B;
        float vz = vec[3*i+2] * INV_B;
        float ps = pol[s] * INV_B3;
        float pd = pol[d] * INV_B3;
        float r2 = r * r;
        float r3 = r2 * r;
        float u  = r3 * rsqrtf(ps * pd);
        float em = __expf(-DM * u);
        float l3m = 1.0f - em;
        float l5m = 1.0f - (1.0f + DM * u) * em;
        float inv_r3 = 1.0f / r3;
        float inv_r5 = inv_r3 / r2;
        float c1 = l3m * inv_r3;                    // >= ~1.2e-4 always (nonzero flag)
        float sw = sqrtf(3.0f * l5m * inv_r5);
        float ec = (1.0f - __expf(-DF * u)) * chg[d] * inv_r3;
        float g  = ec / sw;
        int slot = atomicAdd(&cur[s >> 8], 1);      // LDS cursor
        uint4 rc;
        rc.x = (unsigned)(d | ((s & 255) << 20));
        rc.y = __float_as_uint(c1);
        rc.z = packh2(sw * vx, sw * vy);
        rc.w = packh2(sw * vz, g);
        recs[slot] = rc;
    }
    __syncthreads();
    // fill pad slots with zero records (c1==0 marks dummy; harmless everywhere)
    for (int b = tid; b < nbuck; b += blockDim.x) {
        int base = hoffpad[b * nblk + blk];
        int end  = base + hpad[b * nblk + blk];
        for (int s = cur[b]; s < end; ++s) recs[s] = make_uint4(0, 0, 0, 0);
    }
}

// ---------------- per-bucket counting sort -> tight row-CSR, 12B records ----------------

__global__ void sort_kernel(const int* __restrict__ bktptr, const int* __restrict__ hoffraw,
                            int nblk, const uint4* __restrict__ recs_raw,
                            unsigned* __restrict__ srt, float* __restrict__ gsrt,
                            int* __restrict__ rowbeg, int* __restrict__ rowend, int N)
{
    __shared__ int hist[256];
    __shared__ int scn[256];
    __shared__ int cur[256];
    int tid = threadIdx.x, b = blockIdx.x;
    int j0 = bktptr[b], j1 = bktptr[b + 1];
    int tight0 = hoffraw[b * nblk];                 // tight start of this bucket
    if (tid < 256) hist[tid] = 0;
    __syncthreads();
    for (int j = j0 + tid; j < j1; j += blockDim.x) {
        uint4 rc = recs_raw[j];
        if (rc.y) atomicAdd(&hist[rc.x >> 20], 1);
    }
    __syncthreads();
    if (tid < 256) scn[tid] = hist[tid];
    __syncthreads();
    for (int off = 1; off < 256; off <<= 1) {
        int t = 0;
        if (tid < 256 && tid >= off) t = scn[tid - off];
        __syncthreads();
        if (tid < 256) scn[tid] += t;
        __syncthreads();
    }
    if (tid < 256) {
        int cnt = hist[tid];
        int beg = tight0 + scn[tid] - cnt;          // exclusive
        cur[tid] = beg;
        int row = b * 256 + tid;
        if (row < N) { rowbeg[row] = beg; rowend[row] = beg + cnt; }
    }
    __syncthreads();
    for (int j = j0 + tid; j < j1; j += blockDim.x) {
        uint4 rc = recs_raw[j];
        if (rc.y) {
            int slot = atomicAdd(&cur[rc.x >> 20], 1);
            float c1 = __uint_as_float(rc.y);
            float wx = unph_lo(rc.z);               // f16 round-trip: lossless
            srt[3*slot+0] = rc.x;
            srt[3*slot+1] = packh2(c1, wx);
            srt[3*slot+2] = rc.w;                   // keep low=wz? NO: rc.w = {wz, g}
            // overwrite: we need {wy, wz}
            srt[3*slot+2] = packh2(unph_hi(rc.z), unph_lo(rc.w));
            gsrt[slot] = unph_hi(rc.w);
        }
    }
}

// ---------------- iterate: row-CSR gather, 16 lanes/row, no atomics ----------------

__global__ void e0g_kernel(const int* __restrict__ rowbeg, const int* __restrict__ rowend,
                           const unsigned* __restrict__ srt, const float* __restrict__ gsrt,
                           const float* __restrict__ pol,
                           float4* __restrict__ E0, float4* __restrict__ mu, int N)
{
    int tid  = threadIdx.x;
    int lane = tid & 15;
    int row  = (blockIdx.x * blockDim.x + tid) >> 4;
    if (row >= N) return;
    int r0 = rowbeg[row], r1 = rowend[row];
    float sx = 0.f, sy = 0.f, sz = 0.f;
    for (int j = r0 + lane; j < r1; j += 16) {
        unsigned w0 = srt[3*j+1];
        unsigned w1 = srt[3*j+2];
        float g = gsrt[j];
        sx += g * unph_hi(w0);
        sy += g * unph_lo(w1);
        sz += g * unph_hi(w1);
    }
    for (int m = 8; m >= 1; m >>= 1) {
        sx += __shfl_xor(sx, m);
        sy += __shfl_xor(sy, m);
        sz += __shfl_xor(sz, m);
    }
    if (lane == 0) {
        E0[row] = make_float4(sx, sy, sz, 0.f);
        float a = pol[row] * INV_B3;
        mu[row] = make_float4(a * sx, a * sy, a * sz, 0.f);
    }
}

__global__ void mvg_kernel(const int* __restrict__ rowbeg, const int* __restrict__ rowend,
                           const unsigned* __restrict__ srt, const float4* __restrict__ E0,
                           const float* __restrict__ pol,
                           const float4* __restrict__ mu_in, float4* __restrict__ mu_out,
                           float* __restrict__ energy, int N, int final_iter)
{
    int tid  = threadIdx.x;
    int lane = tid & 15;
    int row  = (blockIdx.x * blockDim.x + tid) >> 4;
    if (row >= N) return;
    int r0 = rowbeg[row], r1 = rowend[row];
    float ax = 0.f, ay = 0.f, az = 0.f;
    for (int j = r0 + lane; j < r1; j += 16) {
        unsigned pk = srt[3*j+0];
        unsigned w0 = srt[3*j+1];
        unsigned w1 = srt[3*j+2];
        float4 m = mu_in[pk & 0xFFFFF];             // random 16B, L2-resident 1.6MB
        float c1 = unph_lo(w0);
        float wx = unph_hi(w0), wy = unph_lo(w1), wz = unph_hi(w1);
        float dot = wx * m.x + wy * m.y + wz * m.z;
        ax += c1 * m.x - dot * wx;
        ay += c1 * m.y - dot * wy;
        az += c1 * m.z - dot * wz;
    }
    for (int msk = 8; msk >= 1; msk >>= 1) {
        ax += __shfl_xor(ax, msk);
        ay += __shfl_xor(ay, msk);
        az += __shfl_xor(az, msk);
    }
    if (lane == 0) {
        float4 e0 = E0[row];
        float a = pol[row] * INV_B3;
        float mx = a * (e0.x - ax);
        float my = a * (e0.y - ay);
        float mz = a * (e0.z - az);
        mu_out[row] = make_float4(mx, my, mz, 0.f);
        if (final_iter)
            energy[row] = -0.5f * (mx * e0.x + my * e0.y + mz * e0.z);
    }
}

// ---------------- middle path: bucket iterate on padded recs (v5) ----------------

__global__ void e0b_kernel(const int* __restrict__ bktptr, const uint4* __restrict__ recs,
                           const float* __restrict__ pol,
                           float4* __restrict__ E0, float4* __restrict__ mu, int N)
{
    __shared__ float acc[256 * 3];
    int tid = threadIdx.x, b = blockIdx.x;
    for (int k = tid; k < 768; k += 256) acc[k] = 0.f;
    __syncthreads();
    int j0 = bktptr[b], j1 = bktptr[b + 1];
    for (int j = j0 + tid; j < j1; j += 256) {
        uint4 rc = recs[j];
        int lr = (int)(rc.x >> 20) & 255;
        float g = unph_hi(rc.w);
        atomicAdd(&acc[lr*3+0], g * unph_lo(rc.z));
        atomicAdd(&acc[lr*3+1], g * unph_hi(rc.z));
        atomicAdd(&acc[lr*3+2], g * unph_lo(rc.w));
    }
    __syncthreads();
    int r = b * 256 + tid;
    if (r < N) {
        float ax = acc[tid*3], ay = acc[tid*3+1], az = acc[tid*3+2];
        E0[r] = make_float4(ax, ay, az, 0.f);
        float a = pol[r] * INV_B3;
        mu[r] = make_float4(a * ax, a * ay, a * az, 0.f);
    }
}

__global__ void mvb_kernel(const int* __restrict__ bktptr, const uint4* __restrict__ recs,
                           const float4* __restrict__ E0, const float* __restrict__ pol,
                           const float4* __restrict__ mu_in, float4* __restrict__ mu_out,
                           float* __restrict__ energy, int N, int final_iter)
{
    __shared__ float acc[256 * 3];
    int tid = threadIdx.x, b = blockIdx.x;
    for (int k = tid; k < 768; k += 256) acc[k] = 0.f;
    __syncthreads();
    int j0 = bktptr[b], j1 = bktptr[b + 1];
    for (int j = j0 + tid; j < j1; j += 256) {
        uint4 rc = recs[j];
        float4 m = mu_in[rc.x & 0xFFFFF];
        float c1 = __uint_as_float(rc.y);
        float wx = unph_lo(rc.z), wy = unph_hi(rc.z), wz = unph_lo(rc.w);
        float dot = wx * m.x + wy * m.y + wz * m.z;
        int lr = (int)(rc.x >> 20) & 255;
        atomicAdd(&acc[lr*3+0], c1 * m.x - dot * wx);
        atomicAdd(&acc[lr*3+1], c1 * m.y - dot * wy);
        atomicAdd(&acc[lr*3+2], c1 * m.z - dot * wz);
    }
    __syncthreads();
    int r = b * 256 + tid;
    if (r < N) {
        float4 e0 = E0[r];
        float a = pol[r] * INV_B3;
        float mx = a * (e0.x - acc[tid*3+0]);
        float my = a * (e0.y - acc[tid*3+1]);
        float mz = a * (e0.z - acc[tid*3+2]);
        mu_out[r] = make_float4(mx, my, mz, 0.f);
        if (final_iter)
            energy[r] = -0.5f * (mx * e0.x + my * e0.y + mz * e0.z);
    }
}

// ---------------- fallback (atomic path, tiny ws) ----------------

__global__ void fb_e0_kernel(const int* esrc, const int* edst, const float* dist,
                             const float* vec, const float* pol, const float* chg,
                             float4* E0, int E)
{
    int e = blockIdx.x * blockDim.x + threadIdx.x;
    if (e >= E) return;
    int s = esrc[e], d = edst[e];
    float r  = dist[e] * INV_B;
    float vx = vec[3*e+0]*INV_B, vy = vec[3*e+1]*INV_B, vz = vec[3*e+2]*INV_B;
    float r3 = r*r*r;
    float u  = r3 * rsqrtf(pol[s]*INV_B3 * pol[d]*INV_B3);
    float ec = (1.0f - __expf(-DF*u)) * chg[d] / r3;
    atomicAdd(&E0[s].x, ec*vx); atomicAdd(&E0[s].y, ec*vy); atomicAdd(&E0[s].z, ec*vz);
}

__global__ void fb_init_kernel(const float* pol, const float4* E0, float4* mu, float4* acc, int N)
{
    int i = blockIdx.x * blockDim.x + threadIdx.x;
    if (i >= N) return;
    float a = pol[i]*INV_B3; float4 e0 = E0[i];
    mu[i]  = make_float4(a*e0.x, a*e0.y, a*e0.z, 0.f);
    acc[i] = make_float4(0.f,0.f,0.f,0.f);
}

__global__ void fb_matvec_kernel(const int* esrc, const int* edst, const float* dist,
                                 const float* vec, const float* pol,
                                 const float4* mu, float4* acc, int E)
{
    int e = blockIdx.x * blockDim.x + threadIdx.x;
    if (e >= E) return;
    int s = esrc[e], d = edst[e];
    float r  = dist[e]*INV_B;
    float vx = vec[3*e+0]*INV_B, vy = vec[3*e+1]*INV_B, vz = vec[3*e+2]*INV_B;
    float r2 = r*r, r3 = r2*r;
    float u  = r3 * rsqrtf(pol[s]*INV_B3 * pol[d]*INV_B3);
    float em = __expf(-DM*u);
    float c1 = (1.0f - em) / r3;
    float c2 = 3.0f * (1.0f - (1.0f + DM*u)*em) / (r3*r2);
    float4 m = mu[d];
    float k = c2 * (vx*m.x + vy*m.y + vz*m.z);
    atomicAdd(&acc[s].x, c1*m.x - k*vx);
    atomicAdd(&acc[s].y, c1*m.y - k*vy);
    atomicAdd(&acc[s].z, c1*m.z - k*vz);
}

__global__ void fb_update_kernel(const float* pol, const float4* E0, float4* acc,
                                 float4* mu, float* energy, int N, int final_iter)
{
    int i = blockIdx.x * blockDim.x + threadIdx.x;
    if (i >= N) return;
    float a = pol[i]*INV_B3; float4 e0 = E0[i]; float4 ac = acc[i];
    float mx = a*(e0.x-ac.x), my = a*(e0.y-ac.y), mz = a*(e0.z-ac.z);
    mu[i]  = make_float4(mx,my,mz,0.f);
    acc[i] = make_float4(0.f,0.f,0.f,0.f);
    if (final_iter) energy[i] = -0.5f*(mx*e0.x + my*e0.y + mz*e0.z);
}

// ---------------- launch ----------------

static inline size_t align_up(size_t x, size_t a) { return (x + a - 1) & ~(a - 1); }

extern "C" void kernel_launch(void* const* d_in, const int* in_sizes, int n_in,
                              void* d_out, int out_size, void* d_ws, size_t ws_size,
                              hipStream_t stream)
{
    // inputs: species, edge_src, edge_dst, distances, vec, polarisability, charges
    const int*   esrc = (const int*)  d_in[1];
    const int*   edst = (const int*)  d_in[2];
    const float* dist = (const float*)d_in[3];
    const float* vec  = (const float*)d_in[4];
    const float* pol  = (const float*)d_in[5];
    const float* chg  = (const float*)d_in[6];
    const int E = in_sizes[1];
    const int N = in_sizes[5];
    float* out = (float*)d_out;

    const int nbuck = (N + 255) >> 8;                  // 391
    const int nblk  = (E + CHUNK - 1) / CHUNK;         // 196
    const int nScan = nbuck * nblk;                    // ~77k
    const int g1    = (nScan + SCAN_B - 1) / SCAN_B;   // ~150
    const size_t Epad = (size_t)E + 7u * (size_t)nScan;

    // workspace layout: middle-path arrays first, sort-path extras last
    char* ws = (char*)d_ws;
    size_t off = 0;
    auto carve = [&](size_t bytes) { size_t o = off; off = align_up(off + bytes, 256); return o; };
    size_t o_hpad    = carve((size_t)nScan * 4);
    size_t o_hoffpad = carve((size_t)nScan * 4);
    size_t o_bsum1   = carve(512 * 4);
    size_t o_bkt     = carve((size_t)(nbuck + 1) * 4);
    size_t o_E0      = carve((size_t)N * 16);
    size_t o_mua     = carve((size_t)N * 16);
    size_t o_mub     = carve((size_t)N * 16);
    size_t o_hraw    = carve((size_t)nScan * 4);
    size_t o_recsraw = carve(Epad * 16);
    size_t need_mid  = off;
    size_t o_hoffraw = carve((size_t)nScan * 4);
    size_t o_bsum2   = carve(512 * 4);
    size_t o_rowbeg  = carve((size_t)N * 4);
    size_t o_rowend  = carve((size_t)N * 4);
    size_t o_srt     = carve((size_t)E * 12);
    size_t o_gsrt    = carve((size_t)E * 4);
    size_t need_sort = off;

    bool shape_ok = (nbuck <= MAXBUCK) && (g1 <= 512) && (nbuck >= 1) && (N < (1 << 20));
    bool ok_sort = shape_ok && (ws_size >= need_sort);
    bool ok_mid  = shape_ok && (ws_size >= need_mid);

    if (ok_sort || ok_mid) {
        int*    hpad    = (int*)   (ws + o_hpad);
        int*    hoffpad = (int*)   (ws + o_hoffpad);
        int*    bsum1   = (int*)   (ws + o_bsum1);
        int*    bktptr  = (int*)   (ws + o_bkt);
        float4* E0      = (float4*)(ws + o_E0);
        float4* mu_a    = (float4*)(ws + o_mua);
        float4* mu_b    = (float4*)(ws + o_mub);
        int*    hraw    = (int*)   (ws + o_hraw);
        uint4*  recsraw = (uint4*) (ws + o_recsraw);

        bhist_kernel<<<nblk, BUILD_T, 0, stream>>>(esrc, hraw, hpad, E, nbuck, nblk);
        scan1_kernel<<<g1, SCAN_B, 0, stream>>>(hpad, hoffpad, bsum1, nScan);
        scan2_kernel<<<1, 512, 0, stream>>>(bsum1, g1);
        scan3_kernel<<<g1, SCAN_B, 0, stream>>>(hoffpad, bsum1, nScan);
        bktptr_kernel<<<(nbuck + 256) / 256, 256, 0, stream>>>(hoffpad, hpad, bktptr,
                                                               nbuck, nblk, nScan);
        build_kernel<<<nblk, BUILD_T, 0, stream>>>(esrc, edst, dist, vec, pol, chg,
                                                   hoffpad, hpad, recsraw, E, nbuck, nblk);

        if (ok_sort) {
            int*      hoffraw = (int*)     (ws + o_hoffraw);
            int*      bsum2   = (int*)     (ws + o_bsum2);
            int*      rowbeg  = (int*)     (ws + o_rowbeg);
            int*      rowend  = (int*)     (ws + o_rowend);
            unsigned* srt     = (unsigned*)(ws + o_srt);
            float*    gsrt    = (float*)   (ws + o_gsrt);

            scan1_kernel<<<g1, SCAN_B, 0, stream>>>(hraw, hoffraw, bsum2, nScan);
            scan2_kernel<<<1, 512, 0, stream>>>(bsum2, g1);
            scan3_kernel<<<g1, SCAN_B, 0, stream>>>(hoffraw, bsum2, nScan);
            sort_kernel<<<nbuck, 512, 0, stream>>>(bktptr, hoffraw, nblk, recsraw,
                                                   srt, gsrt, rowbeg, rowend, N);

            const int NG16 = (N + 15) / 16;
            e0g_kernel<<<NG16, 256, 0, stream>>>(rowbeg, rowend, srt, gsrt, pol, E0, mu_a, N);
            float4* min_ = mu_a; float4* mout_ = mu_b;
            for (int it = 0; it < NITER; ++it) {
                mvg_kernel<<<NG16, 256, 0, stream>>>(rowbeg, rowend, srt, E0, pol,
                                                     min_, mout_, out, N, it == NITER - 1);
                float4* t = min_; min_ = mout_; mout_ = t;
            }
        } else {
            e0b_kernel<<<nbuck, 256, 0, stream>>>(bktptr, recsraw, pol, E0, mu_a, N);
            float4* min_ = mu_a; float4* mout_ = mu_b;
            for (int it = 0; it < NITER; ++it) {
                mvb_kernel<<<nbuck, 256, 0, stream>>>(bktptr, recsraw, E0, pol,
                                                      min_, mout_, out, N, it == NITER - 1);
                float4* t = min_; min_ = mout_; mout_ = t;
            }
        }
    } else {
        // fallback: atomic scatter path (needs 48B/node)
        float4* E0  = (float4*)(ws);
        float4* mu  = (float4*)(ws + (size_t)N * 16);
        float4* acc = (float4*)(ws + (size_t)N * 32);
        const int EB = 256, NB = 256;
        const int EG = (E + EB - 1) / EB;
        const int NG = (N + NB - 1) / NB;
        hipMemsetAsync(E0, 0, (size_t)N * 16, stream);
        fb_e0_kernel<<<EG, EB, 0, stream>>>(esrc, edst, dist, vec, pol, chg, E0, E);
        fb_init_kernel<<<NG, NB, 0, stream>>>(pol, E0, mu, acc, N);
        for (int it = 0; it < NITER; ++it) {
            fb_matvec_kernel<<<EG, EB, 0, stream>>>(esrc, edst, dist, vec, pol, mu, acc, E);
            fb_update_kernel<<<NG, NB, 0, stream>>>(pol, E0, acc, mu, out, N, it == NITER - 1);
        }
    }
}